// Round 12
// baseline (345.186 us; speedup 1.0000x reference)
//
#include <hip/hip_runtime.h>

typedef __bf16 bf16;
typedef __bf16 bf16x4 __attribute__((ext_vector_type(4)));
typedef __bf16 bf16x8 __attribute__((ext_vector_type(8)));
typedef float  f32x4  __attribute__((ext_vector_type(4)));

#define TOKENS 16384
#define D_IN   4096
#define D_OUT  4096
#define RANK   512

// Async global->LDS, 16B per lane. LDS dest wave-uniform base + lane*16;
// global SOURCE is per-lane (swizzles applied by permuting the source).
__device__ inline void gload_lds16(const void* g, void* l) {
    __builtin_amdgcn_global_load_lds((const __attribute__((address_space(1))) void*)g,
                                     (__attribute__((address_space(3))) void*)l,
                                     16, 0, 0);
}

// ---------------------------------------------------------------------------
// Prep 1: Vst[r][k'] = bf16(V[k][r] * sigma[r]), PRE-SWIZZLED (verified:
//   conflicts -> 0). Within each 64-k block: k -> k^((r&7)<<3).
// ---------------------------------------------------------------------------
__global__ __launch_bounds__(256) void vt_scale(const float* __restrict__ V,
                                                const float* __restrict__ sg,
                                                bf16* __restrict__ Vst) {
    __shared__ float tile[64][65];
    const int tx = threadIdx.x & 63;
    const int ty = threadIdx.x >> 6;
    const int kb = blockIdx.x * 64;
    const int rb = blockIdx.y * 64;
    const float s = sg[rb + tx];
#pragma unroll
    for (int i = ty; i < 64; i += 4)
        tile[i][tx] = V[(size_t)(kb + i) * RANK + rb + tx] * s;
    __syncthreads();
#pragma unroll
    for (int i = ty; i < 64; i += 4) {
        int r = rb + i;
        int kp = kb + (tx ^ ((r & 7) << 3));
        Vst[(size_t)r * D_IN + kp] = (bf16)tile[tx][i];
    }
}

// ---------------------------------------------------------------------------
// Prep 2: Ub[n][k'] = bf16(U[n][k]), PRE-SWIZZLED for GEMM2's B staging.
// ---------------------------------------------------------------------------
__global__ __launch_bounds__(256) void cvt_u_swz(const float* __restrict__ U,
                                                 bf16* __restrict__ Ub) {
    int g = blockIdx.x * 256 + threadIdx.x;      // 8-elem granule id
    int n = g >> 6;
    int c = g & 63;
    int blk = c >> 3, q = c & 7;
    const float* src = U + (size_t)n * RANK + c * 8;
    f32x4 v0 = *(const f32x4*)src;
    f32x4 v1 = *(const f32x4*)(src + 4);
    bf16x8 b;
    b[0] = (bf16)v0[0]; b[1] = (bf16)v0[1]; b[2] = (bf16)v0[2]; b[3] = (bf16)v0[3];
    b[4] = (bf16)v1[0]; b[5] = (bf16)v1[1]; b[6] = (bf16)v1[2]; b[7] = (bf16)v1[3];
    *(bf16x8*)(Ub + (size_t)n * RANK + blk * 64 + ((q ^ (n & 7)) * 8)) = b;
}

// ---------------------------------------------------------------------------
// Prep 3: Xb = bf16(x), PRE-SWIZZLED (granule q of each 64-k block ->
//   q ^ (row&7)) so gemm1's linear gload_lds lands it LDS-swizzled.
//   Streaming, grid-stride, ~384 MB total traffic.
// ---------------------------------------------------------------------------
__global__ __launch_bounds__(256) void cvt_x_swz(const float* __restrict__ X,
                                                 bf16* __restrict__ Xb) {
    const int ng = TOKENS * (D_IN / 8);          // 8.4M granules
    const int stride = gridDim.x * 256;
    for (int i = blockIdx.x * 256 + threadIdx.x; i < ng; i += stride) {
        int row = i >> 9;                        // 512 granules per row
        int g   = i & 511;
        f32x4 v0 = *(const f32x4*)(X + (size_t)i * 8);
        f32x4 v1 = *(const f32x4*)(X + (size_t)i * 8 + 4);
        bf16x8 b;
        b[0] = (bf16)v0[0]; b[1] = (bf16)v0[1]; b[2] = (bf16)v0[2]; b[3] = (bf16)v0[3];
        b[4] = (bf16)v1[0]; b[5] = (bf16)v1[1]; b[6] = (bf16)v1[2]; b[7] = (bf16)v1[3];
        int blk = g >> 3, q = g & 7;
        *(bf16x8*)&Xb[(size_t)row * D_IN + blk * 64 + ((q ^ (row & 7)) * 8)] = b;
    }
}

// ---------------------------------------------------------------------------
// GEMM1 — clone of the VALIDATED gemm2_8p schedule, all-bf16 operands:
//   T = bf16( Xb @ Vst^T ).  BM=256, BN=128 -> grid 64x4 = 256 (1 block/CU,
//   no split-K). 512 thr = 8 waves (4M x 2N), wave tile 64x64 (4x4 frags).
//   2-dbuf LDS 96 KB (A 2x32, B 2x16). 6 DMAs/step; steady-state wait
//   vmcnt(6), NEVER 0 until tail; 4 quadrant phases, no intra-phase
//   barriers; T5 setprio. K=4096 -> 64-step pipeline. Sources pre-swizzled;
//   T written pre-swizzled for gemm2_8p.
// ---------------------------------------------------------------------------
__global__ __launch_bounds__(512, 1) void gemm1_k8(const bf16* __restrict__ A,
                                                   const bf16* __restrict__ B,
                                                   bf16* __restrict__ T,
                                                   int M, int N, int K) {
    __shared__ bf16 Al[2][256 * 64];   // 32 KB x2
    __shared__ bf16 Bl[2][128 * 64];   // 16 KB x2

    const int t   = threadIdx.x;       // 0..511
    const int l   = t & 63;
    const int wid = t >> 6;
    const int wm  = wid >> 1;          // 0..3 (M)
    const int wn  = wid & 1;           // 0..1 (N)
    const int lr  = l & 15;
    const int kg  = l >> 4;
    const int sxor = (lr & 7) << 3;

    // XCD-aware bijective swizzle (nwg=256, %8==0)
    const int nwg = gridDim.x;
    const int bid = blockIdx.x;
    const int cpx = nwg >> 3;
    const int swz = (bid & 7) * cpx + (bid >> 3);
    const int ntn = N >> 7;            // 4 n-tiles of 128
    const int tm  = (swz / ntn) << 8;  // BM=256
    const int tn  = (swz % ntn) << 7;  // BN=128

    // staging: A rounds c=0..3 rows c*64+(t>>3); B rounds c=0..1; granule t&7
    const bf16* Apt = A + (size_t)(tm + (t >> 3)) * K + (t & 7) * 8;
    const bf16* Bpt = B + (size_t)(tn + (t >> 3)) * K + (t & 7) * 8;
    const int ldst = t * 8;

    const int NT = K >> 6;             // 64

    f32x4 acc[4][4] = {};
    bf16x8 aq[2][2], bq[2][2];

#define STAGE1(BUF, KT)                                                        \
    _Pragma("unroll") for (int c = 0; c < 2; ++c) {                            \
        gload_lds16(Apt + (KT) + (size_t)(c * 64) * K, &Al[BUF][c * 4096 + ldst]); \
        gload_lds16(Bpt + (KT) + (size_t)(c * 64) * K, &Bl[BUF][c * 4096 + ldst]); \
    }                                                                          \
    _Pragma("unroll") for (int c = 2; c < 4; ++c)                              \
        gload_lds16(Apt + (KT) + (size_t)(c * 64) * K, &Al[BUF][c * 4096 + ldst]);

#define RD_A1(BUF, QM)                                                         \
    _Pragma("unroll") for (int f = 0; f < 2; ++f)                              \
    _Pragma("unroll") for (int ks = 0; ks < 2; ++ks)                           \
        aq[f][ks] = *(const bf16x8*)&Al[BUF][(wm * 64 + ((QM) * 2 + f) * 16 + lr) * 64 + \
                                            ((ks * 32 + kg * 8) ^ sxor)];

#define RD_B1(BUF, QN)                                                         \
    _Pragma("unroll") for (int f = 0; f < 2; ++f)                              \
    _Pragma("unroll") for (int ks = 0; ks < 2; ++ks)                           \
        bq[f][ks] = *(const bf16x8*)&Bl[BUF][(wn * 64 + ((QN) * 2 + f) * 16 + lr) * 64 + \
                                            ((ks * 32 + kg * 8) ^ sxor)];

#define MM1(QM, QN)                                                            \
    __builtin_amdgcn_s_setprio(1);                                             \
    _Pragma("unroll") for (int ks = 0; ks < 2; ++ks)                           \
    _Pragma("unroll") for (int f = 0; f < 2; ++f)                              \
    _Pragma("unroll") for (int g = 0; g < 2; ++g)                              \
        acc[(QM) * 2 + f][(QN) * 2 + g] = __builtin_amdgcn_mfma_f32_16x16x32_bf16( \
            aq[f][ks], bq[g][ks], acc[(QM) * 2 + f][(QN) * 2 + g], 0, 0, 0);   \
    __builtin_amdgcn_s_setprio(0);

    // ---- prologue: stage tiles 0,1; wait tile 0 only (6 newest in flight) ----
    STAGE1(0, 0);
    STAGE1(1, 64);
    asm volatile("s_waitcnt vmcnt(6)" ::: "memory");
    __builtin_amdgcn_sched_barrier(0);
    __builtin_amdgcn_s_barrier();
    __builtin_amdgcn_sched_barrier(0);

    for (int i = 0; i < NT; ++i) {
        const int p = i & 1;
        RD_A1(p, 0); RD_B1(p, 0); MM1(0, 0);
        RD_B1(p, 1);              MM1(0, 1);
        RD_A1(p, 1); RD_B1(p, 0); MM1(1, 0);
        RD_B1(p, 1);              MM1(1, 1);

        if (i + 1 < NT) {
            __builtin_amdgcn_sched_barrier(0);
            __builtin_amdgcn_s_barrier();      // all waves done reading buf p
            __builtin_amdgcn_sched_barrier(0);
            if (i + 2 < NT) {
                STAGE1(p, (i + 2) * 64);       // refill freed buffer
                asm volatile("s_waitcnt vmcnt(6)" ::: "memory");  // tile i+1 landed
            } else {
                asm volatile("s_waitcnt vmcnt(0)" ::: "memory");  // tail drain
            }
            __builtin_amdgcn_sched_barrier(0);
            __builtin_amdgcn_s_barrier();      // publish buf p^1
            __builtin_amdgcn_sched_barrier(0);
        }
    }

    // ---- T-write, PRE-SWIZZLED for gemm2_8p: col ^= ((row&7)<<3) ----
    const int r0 = tm + wm * 64 + kg * 4;
    const int c0 = tn + wn * 64 + lr;
#pragma unroll
    for (int fm = 0; fm < 4; ++fm)
#pragma unroll
        for (int fn = 0; fn < 4; ++fn)
#pragma unroll
            for (int r = 0; r < 4; ++r) {
                int row = r0 + fm * 16 + r;
                int col = (c0 + fn * 16) ^ ((row & 7) << 3);
                T[(size_t)row * N + col] = (bf16)acc[fm][fn][r];
            }
#undef STAGE1
#undef RD_A1
#undef RD_B1
#undef MM1
}

// ---------------------------------------------------------------------------
// GEMM2 — 256x256 multi-phase counted pipeline (r9 validated, unchanged).
// ---------------------------------------------------------------------------
__global__ __launch_bounds__(512, 2) void gemm2_8p(const bf16* __restrict__ A,
                                                   const bf16* __restrict__ B,
                                                   float* __restrict__ out,
                                                   int M, int N, int K) {
    __shared__ bf16 Al[2][256 * 64];
    __shared__ bf16 Bl[2][256 * 64];

    const int t   = threadIdx.x;
    const int l   = t & 63;
    const int wid = t >> 6;
    const int wm  = wid >> 2;
    const int wn  = wid & 3;
    const int lr  = l & 15;
    const int kg  = l >> 4;
    const int sxor = (lr & 7) << 3;

    const int nwg = gridDim.x;
    const int bid = blockIdx.x;
    const int cpx = nwg >> 3;
    const int swz = (bid & 7) * cpx + (bid >> 3);
    const int ntn = N >> 8;
    const int tm  = (swz / ntn) << 8;
    const int tn  = (swz % ntn) << 8;

    const bf16* Apt = A + (size_t)(tm + (t >> 3)) * K + (t & 7) * 8;
    const bf16* Bpt = B + (size_t)(tn + (t >> 3)) * K + (t & 7) * 8;
    const int ldst = t * 8;

    const int NT = K >> 6;

    f32x4 acc[8][4] = {};
    bf16x8 aq[4][2], bq[2][2];

#define STAGE(BUF, KT)                                                         \
    _Pragma("unroll") for (int c = 0; c < 4; ++c) {                            \
        gload_lds16(Apt + (KT) + (size_t)(c * 64) * K, &Al[BUF][c * 4096 + ldst]); \
        gload_lds16(Bpt + (KT) + (size_t)(c * 64) * K, &Bl[BUF][c * 4096 + ldst]); \
    }

#define RD_A(BUF, QM)                                                          \
    _Pragma("unroll") for (int f = 0; f < 4; ++f)                              \
    _Pragma("unroll") for (int ks = 0; ks < 2; ++ks)                           \
        aq[f][ks] = *(const bf16x8*)&Al[BUF][(wm * 128 + (QM) * 64 + f * 16 + lr) * 64 + \
                                            ((ks * 32 + kg * 8) ^ sxor)];

#define RD_B(BUF, QN)                                                          \
    _Pragma("unroll") for (int f = 0; f < 2; ++f)                              \
    _Pragma("unroll") for (int ks = 0; ks < 2; ++ks)                           \
        bq[f][ks] = *(const bf16x8*)&Bl[BUF][(wn * 64 + (QN) * 32 + f * 16 + lr) * 64 + \
                                            ((ks * 32 + kg * 8) ^ sxor)];

#define MM(QM, QN)                                                             \
    __builtin_amdgcn_s_setprio(1);                                             \
    _Pragma("unroll") for (int ks = 0; ks < 2; ++ks)                           \
    _Pragma("unroll") for (int fm = 0; fm < 4; ++fm)                           \
    _Pragma("unroll") for (int fn = 0; fn < 2; ++fn)                           \
        acc[(QM) * 4 + fm][(QN) * 2 + fn] = __builtin_amdgcn_mfma_f32_16x16x32_bf16( \
            aq[fm][ks], bq[fn][ks], acc[(QM) * 4 + fm][(QN) * 2 + fn], 0, 0, 0); \
    __builtin_amdgcn_s_setprio(0);

    STAGE(0, 0);
    STAGE(1, 64);
    asm volatile("s_waitcnt vmcnt(8)" ::: "memory");
    __builtin_amdgcn_sched_barrier(0);
    __builtin_amdgcn_s_barrier();
    __builtin_amdgcn_sched_barrier(0);

    for (int i = 0; i < NT; ++i) {
        const int p = i & 1;
        RD_A(p, 0); RD_B(p, 0); MM(0, 0);
        RD_B(p, 1);             MM(0, 1);
        RD_A(p, 1); RD_B(p, 0); MM(1, 0);
        RD_B(p, 1);             MM(1, 1);

        if (i + 1 < NT) {
            __builtin_amdgcn_sched_barrier(0);
            __builtin_amdgcn_s_barrier();
            __builtin_amdgcn_sched_barrier(0);
            if (i + 2 < NT) {
                STAGE(p, (i + 2) * 64);
                asm volatile("s_waitcnt vmcnt(8)" ::: "memory");
            } else {
                asm volatile("s_waitcnt vmcnt(0)" ::: "memory");
            }
            __builtin_amdgcn_sched_barrier(0);
            __builtin_amdgcn_s_barrier();
            __builtin_amdgcn_sched_barrier(0);
        }
    }

    const int r0 = tm + wm * 128 + kg * 4;
    const int c0 = tn + wn * 64 + lr;
#pragma unroll
    for (int fm = 0; fm < 8; ++fm)
#pragma unroll
        for (int fn = 0; fn < 4; ++fn)
#pragma unroll
            for (int r = 0; r < 4; ++r)
                out[(size_t)(r0 + fm * 16 + r) * N + (c0 + fn * 16)] = acc[fm][fn][r];

#undef STAGE
#undef RD_A
#undef RD_B
#undef MM
}

// ---------------------------------------------------------------------------
extern "C" void kernel_launch(void* const* d_in, const int* in_sizes, int n_in,
                              void* d_out, int out_size, void* d_ws, size_t ws_size,
                              hipStream_t stream) {
    const float* x  = (const float*)d_in[0];  // [16384][4096]
    const float* U  = (const float*)d_in[1];  // [4096][512]
    const float* sg = (const float*)d_in[2];  // [512]
    const float* V  = (const float*)d_in[3];  // [4096][512]
    float* out = (float*)d_out;               // [16384][4096] f32

    char* ws = (char*)d_ws;
    bf16* Vst = (bf16*)ws;                    // [512][4096]   = 4 MB (pre-swz)
    bf16* Ub  = (bf16*)(ws + (4u << 20));     // [4096][512]   = 4 MB (pre-swz)
    bf16* T   = (bf16*)(ws + (8u << 20));     // [16384][512]  = 16 MB (pre-swz)
    bf16* Xb  = (bf16*)(ws + (32u << 20));    // [16384][4096] = 128 MB (pre-swz)

    vt_scale<<<dim3(D_IN / 64, RANK / 64), 256, 0, stream>>>(V, sg, Vst);
    cvt_u_swz<<<(D_OUT * RANK / 8) / 256, 256, 0, stream>>>(U, Ub);
    cvt_x_swz<<<2048, 256, 0, stream>>>(x, Xb);

    // GEMM1: T = bf16( Xb @ Vst^T ), 256x128 counted pipeline, grid 256
    gemm1_k8<<<(TOKENS / 256) * (RANK / 128), 512, 0, stream>>>(
        Xb, Vst, T, TOKENS, RANK, D_IN);

    // GEMM2: out = T @ Ub^T (f32), 256x256 counted pipeline, grid 1024
    gemm2_8p<<<(TOKENS / 256) * (D_OUT / 256), 512, 0, stream>>>(
        T, Ub, out, TOKENS, D_OUT, RANK);
}

// Round 13
// 249.572 us; speedup vs baseline: 1.3831x; 1.3831x over previous
//
#include <hip/hip_runtime.h>

typedef __bf16 bf16;
typedef __bf16 bf16x4 __attribute__((ext_vector_type(4)));
typedef __bf16 bf16x8 __attribute__((ext_vector_type(8)));
typedef float  f32x4  __attribute__((ext_vector_type(4)));

#define TOKENS 16384
#define D_IN   4096
#define D_OUT  4096
#define RANK   512

// Async global->LDS, 16B per lane. LDS dest wave-uniform base + lane*16;
// global SOURCE is per-lane (swizzles applied by permuting the source).
__device__ inline void gload_lds16(const void* g, void* l) {
    __builtin_amdgcn_global_load_lds((const __attribute__((address_space(1))) void*)g,
                                     (__attribute__((address_space(3))) void*)l,
                                     16, 0, 0);
}

// ---------------------------------------------------------------------------
// Prep 1: Vst[r][k'] = bf16(V[k][r] * sigma[r]), PRE-SWIZZLED (verified:
//   conflicts -> 0). Within each 64-k block: k -> k^((r&7)<<3).
// ---------------------------------------------------------------------------
__global__ __launch_bounds__(256) void vt_scale(const float* __restrict__ V,
                                                const float* __restrict__ sg,
                                                bf16* __restrict__ Vst) {
    __shared__ float tile[64][65];
    const int tx = threadIdx.x & 63;
    const int ty = threadIdx.x >> 6;
    const int kb = blockIdx.x * 64;
    const int rb = blockIdx.y * 64;
    const float s = sg[rb + tx];
#pragma unroll
    for (int i = ty; i < 64; i += 4)
        tile[i][tx] = V[(size_t)(kb + i) * RANK + rb + tx] * s;
    __syncthreads();
#pragma unroll
    for (int i = ty; i < 64; i += 4) {
        int r = rb + i;
        int kp = kb + (tx ^ ((r & 7) << 3));
        Vst[(size_t)r * D_IN + kp] = (bf16)tile[tx][i];
    }
}

// ---------------------------------------------------------------------------
// Prep 2: Ub[n][k'] = bf16(U[n][k]), PRE-SWIZZLED for GEMM2's B staging:
//   within each 64-k block, 8-elem granule q -> q ^ (n&7).
// ---------------------------------------------------------------------------
__global__ __launch_bounds__(256) void cvt_u_swz(const float* __restrict__ U,
                                                 bf16* __restrict__ Ub) {
    int g = blockIdx.x * 256 + threadIdx.x;      // 8-elem granule id
    int n = g >> 6;
    int c = g & 63;
    int blk = c >> 3, q = c & 7;
    const float* src = U + (size_t)n * RANK + c * 8;
    f32x4 v0 = *(const f32x4*)src;
    f32x4 v1 = *(const f32x4*)(src + 4);
    bf16x8 b;
    b[0] = (bf16)v0[0]; b[1] = (bf16)v0[1]; b[2] = (bf16)v0[2]; b[3] = (bf16)v0[3];
    b[4] = (bf16)v1[0]; b[5] = (bf16)v1[1]; b[6] = (bf16)v1[2]; b[7] = (bf16)v1[3];
    *(bf16x8*)(Ub + (size_t)n * RANK + blk * 64 + ((q ^ (n & 7)) * 8)) = b;
}

// ---------------------------------------------------------------------------
// GEMM1 (measured optimum, 157 µs): T = bf16( A_f32 @ B_bf16^T ).
//   m97 2-barrier loop, 128x128, BK=64, grid 512 (2 blocks/CU — the
//   bytes x concurrency optimum for this shape). A staged as f32 DIRECTLY
//   via global_load_lds (no reg round-trip), cvt at fragment read.
//   Both LDS tiles conflict-free via source swizzles (verified =0).
//   T written pre-swizzled for gemm2_8p's linear gload_lds staging.
// ---------------------------------------------------------------------------
__device__ inline bf16x8 cvt8(f32x4 a, f32x4 b) {
    bf16x8 r;
    r[0] = (bf16)a[0]; r[1] = (bf16)a[1]; r[2] = (bf16)a[2]; r[3] = (bf16)a[3];
    r[4] = (bf16)b[0]; r[5] = (bf16)b[1]; r[6] = (bf16)b[2]; r[7] = (bf16)b[3];
    return r;
}

__global__ __launch_bounds__(256) void gemm1_alds(const float* __restrict__ A,
                                                  const bf16* __restrict__ B,
                                                  bf16* __restrict__ T,
                                                  int M, int N, int K) {
    __shared__ float Afl[128 * 64];   // 32 KB f32 A tile (chunk-swizzled)
    __shared__ bf16  Bl[128 * 64];    // 16 KB bf16 B tile (swizzled via source)

    const int t  = threadIdx.x;
    const int l  = t & 63;
    const int w  = t >> 6;
    const int wr = w >> 1, wc = w & 1;
    const int lr = l & 15;
    const int kg = l >> 4;
    const int sxorB = (lr & 7) << 3;

    const int nwg = gridDim.x;
    const int bid = blockIdx.x;
    const int cpx = nwg >> 3;
    const int swz = (bid & 7) * cpx + (bid >> 3);
    const int ntn = N >> 7;
    const int tm  = (swz / ntn) << 7;
    const int tn  = (swz % ntn) << 7;

    const int arow = t >> 4;             // 0..15 (= row&15 for all rounds)
    const int acr  = t & 15;
    const float* Asrc = A + (size_t)(tm + arow) * K + ((acr ^ arow) << 2);
    const bf16* Bp = B + (size_t)(tn + (t >> 3)) * K + (t & 7) * 8;

    f32x4 acc[4][4] = {};

    for (int kt = 0; kt < K; kt += 64) {
        // ---- stage both tiles purely via async DMA (no reg transit) ----
#pragma unroll
        for (int c = 0; c < 8; ++c)
            gload_lds16(Asrc + kt + (size_t)(c * 16) * K, &Afl[(c * 256 + t) * 4]);
#pragma unroll
        for (int c = 0; c < 4; ++c)
            gload_lds16(Bp + kt + (size_t)(c * 32) * K, &Bl[(c * 256 + t) * 8]);
        __syncthreads();

#pragma unroll
        for (int ks = 0; ks < 2; ++ks) {
            bf16x8 af[4], bfr[4];
            const int q0 = ks * 8 + kg * 2;
#pragma unroll
            for (int f = 0; f < 4; ++f) {
                const float* Arow = &Afl[(wr * 64 + f * 16 + lr) * 64];
                f32x4 h0 = *(const f32x4*)&Arow[(q0 ^ lr) << 2];
                f32x4 h1 = *(const f32x4*)&Arow[((q0 + 1) ^ lr) << 2];
                af[f] = cvt8(h0, h1);
                bfr[f] = *(const bf16x8*)&Bl[(wc * 64 + f * 16 + lr) * 64 +
                                             ((ks * 32 + kg * 8) ^ sxorB)];
            }
#pragma unroll
            for (int fm = 0; fm < 4; ++fm)
#pragma unroll
                for (int fn = 0; fn < 4; ++fn)
                    acc[fm][fn] = __builtin_amdgcn_mfma_f32_16x16x32_bf16(
                        af[fm], bfr[fn], acc[fm][fn], 0, 0, 0);
        }
        __syncthreads();
    }

    // C-write, PRE-SWIZZLED for GEMM2: col ^= ((row&7)<<3) within 64-block.
    const int r0 = tm + wr * 64 + kg * 4;
    const int c0 = tn + wc * 64 + lr;
#pragma unroll
    for (int fm = 0; fm < 4; ++fm)
#pragma unroll
        for (int fn = 0; fn < 4; ++fn)
#pragma unroll
            for (int r = 0; r < 4; ++r) {
                int row = r0 + fm * 16 + r;
                int col = (c0 + fn * 16) ^ ((row & 7) << 3);
                T[(size_t)row * N + col] = (bf16)acc[fm][fn][r];
            }
}

// ---------------------------------------------------------------------------
// GEMM2 — 256x256 multi-phase counted pipeline (validated, ~90 µs):
//   512 thr = 8 waves (2M x 4N), wave tile 128x64. 2-dbuf 128 KB LDS.
//   4 quadrant phases per K-tile, no intra-phase barriers; stage one tile
//   ahead; steady-state wait vmcnt(8), NEVER 0 until tail; T5 setprio.
//   A (=T) and B (=Ub) pre-swizzled in HBM; frag reads XOR (lr&7)<<3.
// ---------------------------------------------------------------------------
__global__ __launch_bounds__(512, 2) void gemm2_8p(const bf16* __restrict__ A,
                                                   const bf16* __restrict__ B,
                                                   float* __restrict__ out,
                                                   int M, int N, int K) {
    __shared__ bf16 Al[2][256 * 64];
    __shared__ bf16 Bl[2][256 * 64];

    const int t   = threadIdx.x;
    const int l   = t & 63;
    const int wid = t >> 6;
    const int wm  = wid >> 2;
    const int wn  = wid & 3;
    const int lr  = l & 15;
    const int kg  = l >> 4;
    const int sxor = (lr & 7) << 3;

    const int nwg = gridDim.x;
    const int bid = blockIdx.x;
    const int cpx = nwg >> 3;
    const int swz = (bid & 7) * cpx + (bid >> 3);
    const int ntn = N >> 8;
    const int tm  = (swz / ntn) << 8;
    const int tn  = (swz % ntn) << 8;

    const bf16* Apt = A + (size_t)(tm + (t >> 3)) * K + (t & 7) * 8;
    const bf16* Bpt = B + (size_t)(tn + (t >> 3)) * K + (t & 7) * 8;
    const int ldst = t * 8;

    const int NT = K >> 6;

    f32x4 acc[8][4] = {};
    bf16x8 aq[4][2], bq[2][2];

#define STAGE(BUF, KT)                                                         \
    _Pragma("unroll") for (int c = 0; c < 4; ++c) {                            \
        gload_lds16(Apt + (KT) + (size_t)(c * 64) * K, &Al[BUF][c * 4096 + ldst]); \
        gload_lds16(Bpt + (KT) + (size_t)(c * 64) * K, &Bl[BUF][c * 4096 + ldst]); \
    }

#define RD_A(BUF, QM)                                                          \
    _Pragma("unroll") for (int f = 0; f < 4; ++f)                              \
    _Pragma("unroll") for (int ks = 0; ks < 2; ++ks)                           \
        aq[f][ks] = *(const bf16x8*)&Al[BUF][(wm * 128 + (QM) * 64 + f * 16 + lr) * 64 + \
                                            ((ks * 32 + kg * 8) ^ sxor)];

#define RD_B(BUF, QN)                                                          \
    _Pragma("unroll") for (int f = 0; f < 2; ++f)                              \
    _Pragma("unroll") for (int ks = 0; ks < 2; ++ks)                           \
        bq[f][ks] = *(const bf16x8*)&Bl[BUF][(wn * 64 + (QN) * 32 + f * 16 + lr) * 64 + \
                                            ((ks * 32 + kg * 8) ^ sxor)];

#define MM(QM, QN)                                                             \
    __builtin_amdgcn_s_setprio(1);                                             \
    _Pragma("unroll") for (int ks = 0; ks < 2; ++ks)                           \
    _Pragma("unroll") for (int fm = 0; fm < 4; ++fm)                           \
    _Pragma("unroll") for (int fn = 0; fn < 2; ++fn)                           \
        acc[(QM) * 4 + fm][(QN) * 2 + fn] = __builtin_amdgcn_mfma_f32_16x16x32_bf16( \
            aq[fm][ks], bq[fn][ks], acc[(QM) * 4 + fm][(QN) * 2 + fn], 0, 0, 0); \
    __builtin_amdgcn_s_setprio(0);

    STAGE(0, 0);
    STAGE(1, 64);
    asm volatile("s_waitcnt vmcnt(8)" ::: "memory");
    __builtin_amdgcn_sched_barrier(0);
    __builtin_amdgcn_s_barrier();
    __builtin_amdgcn_sched_barrier(0);

    for (int i = 0; i < NT; ++i) {
        const int p = i & 1;
        RD_A(p, 0); RD_B(p, 0); MM(0, 0);
        RD_B(p, 1);             MM(0, 1);
        RD_A(p, 1); RD_B(p, 0); MM(1, 0);
        RD_B(p, 1);             MM(1, 1);

        if (i + 1 < NT) {
            __builtin_amdgcn_sched_barrier(0);
            __builtin_amdgcn_s_barrier();
            __builtin_amdgcn_sched_barrier(0);
            if (i + 2 < NT) {
                STAGE(p, (i + 2) * 64);
                asm volatile("s_waitcnt vmcnt(8)" ::: "memory");
            } else {
                asm volatile("s_waitcnt vmcnt(0)" ::: "memory");
            }
            __builtin_amdgcn_sched_barrier(0);
            __builtin_amdgcn_s_barrier();
            __builtin_amdgcn_sched_barrier(0);
        }
    }

    const int r0 = tm + wm * 128 + kg * 4;
    const int c0 = tn + wn * 64 + lr;
#pragma unroll
    for (int fm = 0; fm < 8; ++fm)
#pragma unroll
        for (int fn = 0; fn < 4; ++fn)
#pragma unroll
            for (int r = 0; r < 4; ++r)
                out[(size_t)(r0 + fm * 16 + r) * N + (c0 + fn * 16)] = acc[fm][fn][r];

#undef STAGE
#undef RD_A
#undef RD_B
#undef MM
}

// ---------------------------------------------------------------------------
extern "C" void kernel_launch(void* const* d_in, const int* in_sizes, int n_in,
                              void* d_out, int out_size, void* d_ws, size_t ws_size,
                              hipStream_t stream) {
    const float* x  = (const float*)d_in[0];  // [16384][4096]
    const float* U  = (const float*)d_in[1];  // [4096][512]
    const float* sg = (const float*)d_in[2];  // [512]
    const float* V  = (const float*)d_in[3];  // [4096][512]
    float* out = (float*)d_out;               // [16384][4096] f32

    char* ws = (char*)d_ws;
    bf16* Vst = (bf16*)ws;                    // [512][4096]  = 4 MB (pre-swizzled)
    bf16* Ub  = (bf16*)(ws + (4u << 20));     // [4096][512]  = 4 MB (pre-swizzled)
    bf16* T   = (bf16*)(ws + (8u << 20));     // [16384][512] = 16 MB (pre-swizzled)

    vt_scale<<<dim3(D_IN / 64, RANK / 64), 256, 0, stream>>>(V, sg, Vst);
    cvt_u_swz<<<(D_OUT * RANK / 8) / 256, 256, 0, stream>>>(U, Ub);

    // GEMM1: T = bf16( x @ Vst^T ), A staged f32 via global_load_lds, grid 512
    gemm1_alds<<<(TOKENS / 128) * (RANK / 128), 256, 0, stream>>>(
        x, Vst, T, TOKENS, RANK, D_IN);

    // GEMM2: out = T @ Ub^T (f32), 256x256 counted pipeline, grid 1024
    gemm2_8p<<<(TOKENS / 256) * (D_OUT / 256), 512, 0, stream>>>(
        T, Ub, out, TOKENS, D_OUT, RANK);
}